// Round 6
// baseline (65509.900 us; speedup 1.0000x reference)
//
#include <hip/hip_runtime.h>

// Problem constants (match reference)
constexpr int Bsz  = 256;   // batch
constexpr int Lf   = 14;    // input features
constexpr int Tt   = 500;   // timesteps
constexpr int Hn   = 1000;  // hidden per layer
constexpr int HT   = 4;     // h-rows per block
constexpr int NBLK = Hn / HT;   // 250 blocks
constexpr int KPAD = 1024;      // spike row stride in bytes (1000..1023 stay 0)
constexpr int NKS  = 4;         // k-splits (block = NKS * 256 threads)

// d_ws layout: [0, SB_BYTES) spike bytes [slot:2][layer:3][b:256][KPAD]
//              [SB_BYTES, +4) barrier counter
constexpr size_t SB_BYTES = (size_t)2 * 3 * Bsz * KPAD; // 1,572,864

// LDS: red[3][NKS-1][Bsz] float4 = 36,864 B; padded request pins 1 block/CU
constexpr size_t SMEM_BYTES = 98304;

typedef float        f32x2 __attribute__((ext_vector_type(2)));
typedef float        f32x4 __attribute__((ext_vector_type(4)));
typedef unsigned int u32x4 __attribute__((ext_vector_type(4)));

__device__ __forceinline__ size_t srow_off(int slot, int layer, int b) {
  return (((size_t)slot * 3 + layer) * Bsz + b) * KPAD;
}

// packed 2xfp32 fma: acc.lo += w.lo*s.lo; acc.hi += w.hi*s.hi
__device__ __forceinline__ void pkfma(f32x2& acc, f32x2 w, f32x2 s) {
  asm("v_pk_fma_f32 %0, %1, %2, %0" : "+v"(acc) : "v"(w), "v"(s));
}

// 128 coherent spike bytes (half range): 8 loads issued, ONE waitall.
__device__ __forceinline__ void spk_half(const unsigned char* p, u32x4 sp[8]) {
  asm volatile(
      "global_load_dwordx4 %0, %8, off sc0 sc1\n\t"
      "global_load_dwordx4 %1, %8, off offset:16 sc0 sc1\n\t"
      "global_load_dwordx4 %2, %8, off offset:32 sc0 sc1\n\t"
      "global_load_dwordx4 %3, %8, off offset:48 sc0 sc1\n\t"
      "global_load_dwordx4 %4, %8, off offset:64 sc0 sc1\n\t"
      "global_load_dwordx4 %5, %8, off offset:80 sc0 sc1\n\t"
      "global_load_dwordx4 %6, %8, off offset:96 sc0 sc1\n\t"
      "global_load_dwordx4 %7, %8, off offset:112 sc0 sc1\n\t"
      "s_waitcnt vmcnt(0)"
      : "=&v"(sp[0]), "=&v"(sp[1]), "=&v"(sp[2]), "=&v"(sp[3]),
        "=&v"(sp[4]), "=&v"(sp[5]), "=&v"(sp[6]), "=&v"(sp[7])
      : "v"(p) : "memory");
}

// coherent 4-byte spike store (write-through to coherence point)
__device__ __forceinline__ void spk_store4(unsigned char* p, unsigned v) {
  asm volatile("global_store_dword %0, %1, off sc0 sc1"
               :: "v"(p), "v"(v) : "memory");
}

// 16 k of one spike word-quad into 1 (or 2) matrices' accumulators.
// w0/w1 point at row j=0, already offset to this chunk's k.
template<bool DUAL>
__device__ __forceinline__ void chunk16(const u32x4 sw,
    const float* __restrict__ w0, f32x2 a0[HT],
    const float* __restrict__ w1, f32x2 a1v[HT]) {
  f32x2 s[8];
#pragma unroll
  for (int q = 0; q < 4; ++q) {
    const unsigned w = sw[q];
    s[2 * q + 0] = f32x2{(float)(w & 0xffu), (float)((w >> 8) & 0xffu)};
    s[2 * q + 1] = f32x2{(float)((w >> 16) & 0xffu), (float)(w >> 24)};
  }
#pragma unroll
  for (int j = 0; j < HT; ++j) {
    const f32x4* r0 = (const f32x4*)(w0 + (size_t)j * Hn);
#pragma unroll
    for (int q = 0; q < 4; ++q) {
      f32x4 qq = r0[q];
      pkfma(a0[j], __builtin_shufflevector(qq, qq, 0, 1), s[2 * q]);
      pkfma(a0[j], __builtin_shufflevector(qq, qq, 2, 3), s[2 * q + 1]);
    }
    if constexpr (DUAL) {
      const f32x4* r1 = (const f32x4*)(w1 + (size_t)j * Hn);
#pragma unroll
      for (int q = 0; q < 4; ++q) {
        f32x4 qq = r1[q];
        pkfma(a1v[j], __builtin_shufflevector(qq, qq, 0, 1), s[2 * q]);
        pkfma(a1v[j], __builtin_shufflevector(qq, qq, 2, 3), s[2 * q + 1]);
      }
    }
  }
}

// 256-k range (this thread's k-quarter) of one spike row into 1-2 matrices.
// sprow/w0/w1 are row bases; k0 = quarter offset. Tail k>=1000 reads zero
// spike padding -> contributes 0 (weights OOB within the same matrix only
// for k<1024*... never: k capped at 1023 < next row start? k max = 1023,
// w row j*Hn+1023 reads into row j+1's first elements, but spike pad = 0
// so the fma adds 0 regardless of the weight value).
template<bool DUAL>
__device__ __forceinline__ void accum_range(const unsigned char* sprow,
    const float* __restrict__ w0, f32x2 a0[HT],
    const float* __restrict__ w1, f32x2 a1v[HT], int k0) {
#pragma unroll 1
  for (int h = 0; h < 2; ++h) {
    const int kh = k0 + h * 128;
    u32x4 sp[8];
    spk_half(sprow + kh, sp);
#pragma unroll
    for (int c = 0; c < 8; ++c)
      chunk16<DUAL>(sp[c], w0 + kh + c * 16, a0, w1 + kh + c * 16, a1v);
  }
}

// LIF (tau=2, v_th=1, hard reset) for 4 neurons; returns packed spike bytes
__device__ __forceinline__ unsigned lif_pack(float v[HT], const float a[HT]) {
  unsigned pack = 0;
#pragma unroll
  for (int j = 0; j < HT; ++j) {
    float vn = v[j] + (a[j] - v[j]) * 0.5f;
    bool sp = (vn >= 1.0f);
    v[j] = sp ? 0.0f : vn;
    pack |= (sp ? 1u : 0u) << (8 * j);
  }
  return pack;
}

__global__ void __launch_bounds__(1024, 4)
snn_coop(const float* __restrict__ x,
         const float* __restrict__ W1, const float* __restrict__ R1,
         const float* __restrict__ W2, const float* __restrict__ R2,
         const float* __restrict__ W3, const float* __restrict__ R3,
         unsigned char* __restrict__ sb,
         unsigned* __restrict__ bar,
         float* __restrict__ out)
{
  extern __shared__ float4 red[];   // [3][NKS-1][Bsz]

  const int tid = threadIdx.x;
  const int b   = tid & 255;                                  // batch
  const int ks  = __builtin_amdgcn_readfirstlane(tid >> 6 >> 2); // k-split 0..3 (uniform)
  const int h0  = blockIdx.x * HT;                            // uniform
  const int k0  = ks * 256;

  const float* W1r = W1 + (size_t)h0 * Lf;
  const float* R1r = R1 + (size_t)h0 * Hn;
  const float* W2r = W2 + (size_t)h0 * Hn;
  const float* R2r = R2 + (size_t)h0 * Hn;
  const float* W3r = W3 + (size_t)h0 * Hn;
  const float* R3r = R3 + (size_t)h0 * Hn;

  float v1[HT], v2[HT], v3[HT];
#pragma unroll
  for (int j = 0; j < HT; ++j) { v1[j] = 0.f; v2[j] = 0.f; v3[j] = 0.f; }

  const float* xb = x + (size_t)b * (Lf * Tt); // x[b][l][t]

  // Diagonal pipeline: phase p -> L1@t=p, L2@t=p-1, L3@t=p-2.
  // Writes in phase p go to slot (p&1); reads from slot ((p-1)&1).
  // Out-of-window layer phases run unguarded on all-zero spike data
  // (harmless: accs stay 0, LIF keeps v=0 / perturbs only dead state).
  for (int p = 0; p < Tt + 2; ++p) {
    const int srd = (p + 1) & 1;
    const int swr = p & 1;

    f32x2 a1[HT], a2[HT], a3[HT];
#pragma unroll
    for (int j = 0; j < HT; ++j) {
      a1[j] = f32x2{0.f, 0.f}; a2[j] = f32x2{0.f, 0.f}; a3[j] = f32x2{0.f, 0.f};
    }
    float xacc[HT] = {0.f, 0.f, 0.f, 0.f};

    if (ks == 3 && p < Tt) {   // feedforward x @ W1^T (k=14), lighter split
#pragma unroll
      for (int l = 0; l < Lf; ++l) {
        const float xv = xb[(size_t)l * Tt + p];
#pragma unroll
        for (int j = 0; j < HT; ++j)
          xacc[j] = fmaf(W1r[j * Lf + l], xv, xacc[j]);
      }
    }

    const unsigned char* s0 = sb + srow_off(srd, 0, b);
    const unsigned char* s1 = sb + srow_off(srd, 1, b);
    const unsigned char* s2 = sb + srow_off(srd, 2, b);

    accum_range<true >(s0, R1r, a1, W2r, a2, k0);  // c1->R1 (L1), s1->W2 (L2)
    accum_range<true >(s1, R2r, a2, W3r, a3, k0);  // c2->R2 (L2), s2->W3 (L3)
    accum_range<false>(s2, R3r, a3, R3r, a3, k0);  // c3->R3 (L3)

    float m1[HT], m2[HT], m3[HT];
#pragma unroll
    for (int j = 0; j < HT; ++j) {
      m1[j] = a1[j][0] + a1[j][1] + xacc[j];
      m2[j] = a2[j][0] + a2[j][1];
      m3[j] = a3[j][0] + a3[j][1];
    }

    if (ks != 0) {
      red[(0 * (NKS - 1) + ks - 1) * Bsz + b] = make_float4(m1[0], m1[1], m1[2], m1[3]);
      red[(1 * (NKS - 1) + ks - 1) * Bsz + b] = make_float4(m2[0], m2[1], m2[2], m2[3]);
      red[(2 * (NKS - 1) + ks - 1) * Bsz + b] = make_float4(m3[0], m3[1], m3[2], m3[3]);
    }
    __syncthreads();

    if (ks == 0) {
#pragma unroll
      for (int q = 0; q < NKS - 1; ++q) {
        float4 r = red[(0 * (NKS - 1) + q) * Bsz + b];
        m1[0] += r.x; m1[1] += r.y; m1[2] += r.z; m1[3] += r.w;
      }
      spk_store4(sb + srow_off(swr, 0, b) + h0, lif_pack(v1, m1));
#pragma unroll
      for (int q = 0; q < NKS - 1; ++q) {
        float4 r = red[(1 * (NKS - 1) + q) * Bsz + b];
        m2[0] += r.x; m2[1] += r.y; m2[2] += r.z; m2[3] += r.w;
      }
      spk_store4(sb + srow_off(swr, 1, b) + h0, lif_pack(v2, m2));
#pragma unroll
      for (int q = 0; q < NKS - 1; ++q) {
        float4 r = red[(2 * (NKS - 1) + q) * Bsz + b];
        m3[0] += r.x; m3[1] += r.y; m3[2] += r.z; m3[3] += r.w;
      }
      spk_store4(sb + srow_off(swr, 2, b) + h0, lif_pack(v3, m3));
    }

    // ---- fence-free grid barrier (no cache invalidation) ----
    asm volatile("s_waitcnt vmcnt(0)" ::: "memory");  // release own stores
    __syncthreads();
    if (tid == 0) {
      __hip_atomic_fetch_add(bar, 1u, __ATOMIC_RELAXED, __HIP_MEMORY_SCOPE_AGENT);
      const unsigned tgt = (unsigned)(p + 1) * NBLK;
      while (__hip_atomic_load(bar, __ATOMIC_RELAXED, __HIP_MEMORY_SCOPE_AGENT) < tgt) {}
    }
    __syncthreads();
  }

  // Output: exp(final v3); [B][H] row-major, float4 store
  if (ks == 0) {
    float4 o = make_float4(expf(v3[0]), expf(v3[1]), expf(v3[2]), expf(v3[3]));
    *(float4*)(out + (size_t)b * Hn + h0) = o;
  }
}

extern "C" void kernel_launch(void* const* d_in, const int* in_sizes, int n_in,
                              void* d_out, int out_size, void* d_ws, size_t ws_size,
                              hipStream_t stream) {
  const float* x  = (const float*)d_in[0];
  const float* W1 = (const float*)d_in[1];
  const float* R1 = (const float*)d_in[2];
  const float* W2 = (const float*)d_in[3];
  const float* R2 = (const float*)d_in[4];
  const float* W3 = (const float*)d_in[5];
  const float* R3 = (const float*)d_in[6];
  float* out = (float*)d_out;

  unsigned char* sbytes = (unsigned char*)d_ws;
  unsigned* bar = (unsigned*)((char*)d_ws + SB_BYTES);

  // allow >64KB dynamic LDS (host-side attribute; graph-capture safe)
  hipFuncSetAttribute((const void*)snn_coop,
                      hipFuncAttributeMaxDynamicSharedMemorySize,
                      (int)SMEM_BYTES);

  // zero spike slots + barrier counter (deterministic per launch/replay)
  hipMemsetAsync(d_ws, 0, SB_BYTES + 64, stream);

  void* args[] = { (void*)&x, (void*)&W1, (void*)&R1, (void*)&W2, (void*)&R2,
                   (void*)&W3, (void*)&R3, (void*)&sbytes, (void*)&bar,
                   (void*)&out };
  hipLaunchCooperativeKernel((const void*)snn_coop, dim3(NBLK), dim3(1024),
                             args, SMEM_BYTES, stream);
}

// Round 8
// 55233.521 us; speedup vs baseline: 1.1861x; 1.1861x over previous
//
#include <hip/hip_runtime.h>

// Problem constants
constexpr int Bsz = 256, Lf = 14, Tt = 500, Hn = 1000;
constexpr int HP = 1024, KP = 1024;     // padded h/k extents
constexpr int NBLK = 256;

// ---- MFMA-path d_ws layout ----
constexpr size_t W_MAT    = (size_t)HP * KP * 2;        // 2 MB bf16 per matrix
constexpr size_t W_SH     = (size_t)HP * KP;            // shorts per matrix
constexpr size_t SB_OFF   = 5 * W_MAT;                  // 10,485,760
constexpr size_t SB_BYTES = (size_t)2 * 3 * Bsz * KP;   // 1,572,864
constexpr size_t BAR_OFF  = SB_OFF + SB_BYTES;          // 12,058,624
constexpr size_t WS_NEED  = BAR_OFF + 64;               // ~12.06 MB

// ---- fallback (round-5 VALU) layout: spikes at 0, bar after ----
constexpr size_t FB_SB_BYTES = (size_t)2 * 3 * Bsz * KP;
constexpr size_t FB_SMEM     = 98304;
constexpr int    FB_NBLK     = 250;
constexpr int    FB_NKS      = 4;

typedef __attribute__((ext_vector_type(8)))  short    short8;  // 8 bf16
typedef __attribute__((ext_vector_type(16))) float    f32x16;
typedef __attribute__((ext_vector_type(2)))  unsigned u32x2;
typedef __attribute__((ext_vector_type(4)))  unsigned u32x4v;

// ======================= prep kernel (bf16 weights) =======================
__device__ __forceinline__ unsigned short f2bf(float f) {
  unsigned u = __builtin_bit_cast(unsigned, f);
  unsigned r = (u + 0x7FFFu + ((u >> 16) & 1u)) >> 16;   // RNE
  return (unsigned short)r;
}

__global__ void prep_w(const float* __restrict__ R1, const float* __restrict__ W2,
                       const float* __restrict__ R2, const float* __restrict__ W3,
                       const float* __restrict__ R3, unsigned char* __restrict__ ws) {
  int id  = blockIdx.x * 256 + threadIdx.x;      // 5 * 2^20 threads
  int mat = id >> 20;
  int rem = id & 0xFFFFF;
  int h   = rem >> 10;
  int k   = rem & 1023;
  const float* src = (mat == 0) ? R1 : (mat == 1) ? W2 : (mat == 2) ? R2
                    : (mat == 3) ? W3 : R3;
  float v = (h < Hn && k < Hn) ? src[(size_t)h * Hn + k] : 0.f;
  ((unsigned short*)ws)[(size_t)mat * W_SH + (size_t)h * KP + k] = f2bf(v);
}

// ======================= MFMA main kernel =======================
__device__ __forceinline__ short8 expand8(u32x2 d) {
  // 8 spike bytes (0/1) -> 8 bf16 (0.0/1.0). pair = b0 | b1<<16; *0x3F80.
  unsigned p0 = __umul24(((d[0] & 0xFFu)         | ((d[0] & 0xFF00u) << 8)), 0x3F80u);
  unsigned p1 = __umul24((((d[0] >> 16) & 0xFFu) | ((d[0] >> 24) << 16)),    0x3F80u);
  unsigned p2 = __umul24(((d[1] & 0xFFu)         | ((d[1] & 0xFF00u) << 8)), 0x3F80u);
  unsigned p3 = __umul24((((d[1] >> 16) & 0xFFu) | ((d[1] >> 24) << 16)),    0x3F80u);
  u32x4v u = {p0, p1, p2, p3};
  return __builtin_bit_cast(short8, u);
}

__device__ __forceinline__ f32x16 MF(short8 a, const unsigned short* wp, f32x16 c) {
  short8 b = *(const short8*)wp;
  return __builtin_amdgcn_mfma_f32_32x32x16_bf16(a, b, c, 0, 0, 0);
}

__global__ void __launch_bounds__(256, 1)
snn_mfma(const float* __restrict__ x, const float* __restrict__ W1,
         unsigned char* __restrict__ ws, float* __restrict__ out)
{
  __shared__ float redF[10240];   // [0,9216): 9 partial C-tiles; [9216,10240): F

  const int tid = threadIdx.x;
  const int l   = tid & 63;
  const int w   = tid >> 6;                    // wave 0..3 (k-split)
  const int lr  = l & 31;                      // A-row (b) / B-col (h)
  const int lg  = l >> 5;                      // k lane-group
  const int blk = blockIdx.x;
  const int bt  = blk >> 5;                            // 0..7
  const int ht  = (blk & 7) * 4 + ((blk >> 3) & 3);    // 0..31 (XCD-grouped)
  const int b0  = bt * 32, h0 = ht * 32;

  unsigned char* sb  = ws + SB_OFF;
  unsigned*      bar = (unsigned*)(ws + BAR_OFF);

  // per-lane bf16 weight fragment pointers: row h0+lr, k offset lg*8
  const unsigned short* wb = (const unsigned short*)ws;
  const size_t wlane = (size_t)(h0 + lr) * KP + lg * 8;
  const unsigned short* wR1 = wb + 0 * W_SH + wlane;
  const unsigned short* wW2 = wb + 1 * W_SH + wlane;
  const unsigned short* wR2 = wb + 2 * W_SH + wlane;
  const unsigned short* wW3 = wb + 3 * W_SH + wlane;
  const unsigned short* wR3 = wb + 4 * W_SH + wlane;

  // W1 rows for feedforward (one h-col per thread), hoisted
  float w1r[Lf];
  {
    int h = h0 + (tid & 31);
#pragma unroll
    for (int t = 0; t < Lf; ++t)
      w1r[t] = (h < Hn) ? W1[(size_t)h * Lf + t] : 0.f;
  }

  f32x16 v1, v2, v3;
#pragma unroll
  for (int j = 0; j < 16; ++j) { v1[j] = 0.f; v2[j] = 0.f; v3[j] = 0.f; }

#pragma unroll 1
  for (int p = 0; p < Tt + 2; ++p) {
    const int srd = (p + 1) & 1;
    const int swr = p & 1;

    // ---- feedforward F = x@W1^T tile into LDS (layer 1, t=p) ----
    // x[b][l][t]: stride-T broadcast loads, L1-cached (never invalidated)
    if (p < Tt) {
#pragma unroll
      for (int q = 0; q < 4; ++q) {
        int fb = (tid >> 5) + 8 * q;
        const float* xr = x + (size_t)(b0 + fb) * Lf * Tt + p;
        float F = 0.f;
#pragma unroll
        for (int t = 0; t < Lf; ++t) F = fmaf(xr[(size_t)t * Tt], w1r[t], F);
        redF[9216 + fb * 32 + (tid & 31)] = F;
      }
    } else {
#pragma unroll
      for (int q = 0; q < 4; ++q)
        redF[9216 + ((tid >> 5) + 8 * q) * 32 + (tid & 31)] = 0.f;
    }

    // ---- MFMA: 3 diagonal layers, k-split across waves ----
    f32x16 acc1, acc2, acc3;
#pragma unroll
    for (int j = 0; j < 16; ++j) { acc1[j] = 0.f; acc2[j] = 0.f; acc3[j] = 0.f; }

    const unsigned char* sA = sb + ((size_t)(srd * 3 + 0) * Bsz + (b0 + lr)) * KP + lg * 8;
    const unsigned char* sB = sb + ((size_t)(srd * 3 + 1) * Bsz + (b0 + lr)) * KP + lg * 8;
    const unsigned char* sC = sb + ((size_t)(srd * 3 + 2) * Bsz + (b0 + lr)) * KP + lg * 8;

#pragma unroll
    for (int half = 0; half < 2; ++half) {
      const int kbb = w * 16 + half * 8;
      const unsigned char* pA = sA + kbb * 16;
      const unsigned char* pB = sB + kbb * 16;
      const unsigned char* pC = sC + kbb * 16;
      u32x2 dA[8], dB[8], dC[8];
      asm volatile(
        "global_load_dwordx2 %0, %24, off sc0 sc1\n\t"
        "global_load_dwordx2 %8, %25, off sc0 sc1\n\t"
        "global_load_dwordx2 %16, %26, off sc0 sc1\n\t"
        "global_load_dwordx2 %1, %24, off offset:16 sc0 sc1\n\t"
        "global_load_dwordx2 %9, %25, off offset:16 sc0 sc1\n\t"
        "global_load_dwordx2 %17, %26, off offset:16 sc0 sc1\n\t"
        "global_load_dwordx2 %2, %24, off offset:32 sc0 sc1\n\t"
        "global_load_dwordx2 %10, %25, off offset:32 sc0 sc1\n\t"
        "global_load_dwordx2 %18, %26, off offset:32 sc0 sc1\n\t"
        "global_load_dwordx2 %3, %24, off offset:48 sc0 sc1\n\t"
        "global_load_dwordx2 %11, %25, off offset:48 sc0 sc1\n\t"
        "global_load_dwordx2 %19, %26, off offset:48 sc0 sc1\n\t"
        "global_load_dwordx2 %4, %24, off offset:64 sc0 sc1\n\t"
        "global_load_dwordx2 %12, %25, off offset:64 sc0 sc1\n\t"
        "global_load_dwordx2 %20, %26, off offset:64 sc0 sc1\n\t"
        "global_load_dwordx2 %5, %24, off offset:80 sc0 sc1\n\t"
        "global_load_dwordx2 %13, %25, off offset:80 sc0 sc1\n\t"
        "global_load_dwordx2 %21, %26, off offset:80 sc0 sc1\n\t"
        "global_load_dwordx2 %6, %24, off offset:96 sc0 sc1\n\t"
        "global_load_dwordx2 %14, %25, off offset:96 sc0 sc1\n\t"
        "global_load_dwordx2 %22, %26, off offset:96 sc0 sc1\n\t"
        "global_load_dwordx2 %7, %24, off offset:112 sc0 sc1\n\t"
        "global_load_dwordx2 %15, %25, off offset:112 sc0 sc1\n\t"
        "global_load_dwordx2 %23, %26, off offset:112 sc0 sc1\n\t"
        "s_waitcnt vmcnt(0)"
        : "=&v"(dA[0]), "=&v"(dA[1]), "=&v"(dA[2]), "=&v"(dA[3]),
          "=&v"(dA[4]), "=&v"(dA[5]), "=&v"(dA[6]), "=&v"(dA[7]),
          "=&v"(dB[0]), "=&v"(dB[1]), "=&v"(dB[2]), "=&v"(dB[3]),
          "=&v"(dB[4]), "=&v"(dB[5]), "=&v"(dB[6]), "=&v"(dB[7]),
          "=&v"(dC[0]), "=&v"(dC[1]), "=&v"(dC[2]), "=&v"(dC[3]),
          "=&v"(dC[4]), "=&v"(dC[5]), "=&v"(dC[6]), "=&v"(dC[7])
        : "v"(pA), "v"(pB), "v"(pC)
        : "memory");
      __builtin_amdgcn_sched_barrier(0);

#pragma unroll
      for (int i = 0; i < 8; ++i) {
        const int ko = (kbb + i) * 16;   // element offset into weight rows
        short8 a0 = expand8(dA[i]);
        short8 a1 = expand8(dB[i]);
        short8 a2 = expand8(dC[i]);
        acc1 = MF(a0, wR1 + ko, acc1);
        acc2 = MF(a0, wW2 + ko, acc2);
        acc2 = MF(a1, wR2 + ko, acc2);
        acc3 = MF(a1, wW3 + ko, acc3);
        acc3 = MF(a2, wR3 + ko, acc3);
      }
    }

    // ---- cross-wave reduce + LIF (wave 0) ----
    if (w != 0) {
      float* dp = &redF[(((w - 1) * 3 + 0) * 64 + l) * 16];
#pragma unroll
      for (int j = 0; j < 16; ++j) {
        dp[j]        = acc1[j];
        dp[1024 + j] = acc2[j];
        dp[2048 + j] = acc3[j];
      }
    }
    __syncthreads();

    if (w == 0) {
#pragma unroll
      for (int ww = 0; ww < 3; ++ww) {
        const float* ps = &redF[((ww * 3 + 0) * 64 + l) * 16];
#pragma unroll
        for (int j = 0; j < 16; ++j) {
          acc1[j] += ps[j];
          acc2[j] += ps[1024 + j];
          acc3[j] += ps[2048 + j];
        }
      }
      unsigned char* o1 = sb + ((size_t)(swr * 3 + 0) * Bsz + b0) * KP + h0 + lr;
      unsigned char* o2 = sb + ((size_t)(swr * 3 + 1) * Bsz + b0) * KP + h0 + lr;
      unsigned char* o3 = sb + ((size_t)(swr * 3 + 2) * Bsz + b0) * KP + h0 + lr;
#pragma unroll
      for (int j = 0; j < 16; ++j) {
        const int row = (j & 3) + 8 * (j >> 2) + 4 * lg;   // C-tile b-row
        float F   = redF[9216 + row * 32 + lr];
        float vn1 = 0.5f * (v1[j] + acc1[j] + F);
        unsigned c1 = (vn1 >= 1.0f) ? 1u : 0u;
        v1[j] = c1 ? 0.f : vn1;
        asm volatile("global_store_byte %0, %1, off sc0 sc1"
                     :: "v"(o1 + (size_t)row * KP), "v"(c1) : "memory");
        float vn2 = 0.5f * (v2[j] + acc2[j]);
        unsigned c2 = (vn2 >= 1.0f) ? 1u : 0u;
        v2[j] = c2 ? 0.f : vn2;
        asm volatile("global_store_byte %0, %1, off sc0 sc1"
                     :: "v"(o2 + (size_t)row * KP), "v"(c2) : "memory");
        float vn3 = 0.5f * (v3[j] + acc3[j]);
        unsigned c3 = (vn3 >= 1.0f) ? 1u : 0u;
        v3[j] = c3 ? 0.f : vn3;
        asm volatile("global_store_byte %0, %1, off sc0 sc1"
                     :: "v"(o3 + (size_t)row * KP), "v"(c3) : "memory");
      }
    }

    // ---- fence-free grid barrier (no cache invalidation) ----
    asm volatile("s_waitcnt vmcnt(0)" ::: "memory");
    __syncthreads();
    if (tid == 0) {
      __hip_atomic_fetch_add(bar, 1u, __ATOMIC_RELAXED, __HIP_MEMORY_SCOPE_AGENT);
      const unsigned tgt = (unsigned)(p + 1) * NBLK;
      while (__hip_atomic_load(bar, __ATOMIC_RELAXED, __HIP_MEMORY_SCOPE_AGENT) < tgt) {}
    }
    __syncthreads();
  }

  // ---- output: exp(final v3) ----
  if (w == 0 && (h0 + lr) < Hn) {
#pragma unroll
    for (int j = 0; j < 16; ++j) {
      const int row = (j & 3) + 8 * (j >> 2) + 4 * lg;
      out[(size_t)(b0 + row) * Hn + h0 + lr] = expf(v3[j]);
    }
  }
}

// ======================= fallback: round-5 VALU kernel =======================
__device__ __forceinline__ size_t fb_srow(int slot, int layer, int b) {
  return (((size_t)slot * 3 + layer) * Bsz + b) * KP;
}
__device__ __forceinline__ void fb_cvt4(unsigned w, float* s) {
  s[0] = (float)(w & 0xffu);
  s[1] = (float)((w >> 8) & 0xffu);
  s[2] = (float)((w >> 16) & 0xffu);
  s[3] = (float)(w >> 24);
}
__device__ __forceinline__ void fb_load64(const unsigned char* p, u32x4v sp[4]) {
  asm volatile(
      "global_load_dwordx4 %0, %4, off sc0 sc1\n\t"
      "global_load_dwordx4 %1, %4, off offset:16 sc0 sc1\n\t"
      "global_load_dwordx4 %2, %4, off offset:32 sc0 sc1\n\t"
      "global_load_dwordx4 %3, %4, off offset:48 sc0 sc1\n\t"
      "s_waitcnt vmcnt(0)"
      : "=&v"(sp[0]), "=&v"(sp[1]), "=&v"(sp[2]), "=&v"(sp[3])
      : "v"(p) : "memory");
}
__device__ __forceinline__ void fb_load40(const unsigned char* p,
                                          u32x4v& a, u32x4v& b, u32x2& c) {
  asm volatile(
      "global_load_dwordx4 %0, %3, off sc0 sc1\n\t"
      "global_load_dwordx4 %1, %3, off offset:16 sc0 sc1\n\t"
      "global_load_dwordx2 %2, %3, off offset:32 sc0 sc1\n\t"
      "s_waitcnt vmcnt(0)"
      : "=&v"(a), "=&v"(b), "=&v"(c) : "v"(p) : "memory");
}
__device__ __forceinline__ void fb_store4(unsigned char* p, unsigned v) {
  asm volatile("global_store_dword %0, %1, off sc0 sc1"
               :: "v"(p), "v"(v) : "memory");
}
__device__ __forceinline__ void fb_fmac16(float acc[4], u32x4v sw,
                                          const float* __restrict__ wr) {
  float s[16];
  fb_cvt4(sw[0], s); fb_cvt4(sw[1], s + 4); fb_cvt4(sw[2], s + 8); fb_cvt4(sw[3], s + 12);
#pragma unroll
  for (int j = 0; j < 4; ++j) {
    const float4* w4 = (const float4*)(wr + (size_t)j * Hn);
    float4 wa = w4[0], wb = w4[1], wc = w4[2], wd = w4[3];
    acc[j] = fmaf(wa.x, s[0],  acc[j]);  acc[j] = fmaf(wa.y, s[1],  acc[j]);
    acc[j] = fmaf(wa.z, s[2],  acc[j]);  acc[j] = fmaf(wa.w, s[3],  acc[j]);
    acc[j] = fmaf(wb.x, s[4],  acc[j]);  acc[j] = fmaf(wb.y, s[5],  acc[j]);
    acc[j] = fmaf(wb.z, s[6],  acc[j]);  acc[j] = fmaf(wb.w, s[7],  acc[j]);
    acc[j] = fmaf(wc.x, s[8],  acc[j]);  acc[j] = fmaf(wc.y, s[9],  acc[j]);
    acc[j] = fmaf(wc.z, s[10], acc[j]);  acc[j] = fmaf(wc.w, s[11], acc[j]);
    acc[j] = fmaf(wd.x, s[12], acc[j]);  acc[j] = fmaf(wd.y, s[13], acc[j]);
    acc[j] = fmaf(wd.z, s[14], acc[j]);  acc[j] = fmaf(wd.w, s[15], acc[j]);
  }
}
__device__ __forceinline__ void fb_fmac8(float acc[4], u32x2 sw,
                                         const float* __restrict__ wr) {
  float s[8];
  fb_cvt4(sw[0], s); fb_cvt4(sw[1], s + 4);
#pragma unroll
  for (int j = 0; j < 4; ++j) {
    const float4* w4 = (const float4*)(wr + (size_t)j * Hn);
    float4 wa = w4[0], wb = w4[1];
    acc[j] = fmaf(wa.x, s[0], acc[j]);  acc[j] = fmaf(wa.y, s[1], acc[j]);
    acc[j] = fmaf(wa.z, s[2], acc[j]);  acc[j] = fmaf(wa.w, s[3], acc[j]);
    acc[j] = fmaf(wb.x, s[4], acc[j]);  acc[j] = fmaf(wb.y, s[5], acc[j]);
    acc[j] = fmaf(wb.z, s[6], acc[j]);  acc[j] = fmaf(wb.w, s[7], acc[j]);
  }
}
__device__ __forceinline__ void fb_accum(float acc[4],
    const unsigned char* __restrict__ srow,
    const float* __restrict__ wrow, int k0, int k1) {
  int kc = k0;
  for (; kc + 64 <= k1; kc += 64) {
    u32x4v sp[4];
    fb_load64(srow + kc, sp);
#pragma unroll
    for (int c = 0; c < 4; ++c)
      fb_fmac16(acc, sp[c], wrow + kc + c * 16);
  }
  if (kc < k1) {
    u32x4v a, b; u32x2 c2;
    fb_load40(srow + kc, a, b, c2);
    fb_fmac16(acc, a, wrow + kc);
    fb_fmac16(acc, b, wrow + kc + 16);
    fb_fmac8(acc, c2, wrow + kc + 32);
  }
}
__device__ __forceinline__ unsigned fb_lif(float v[4], const float a[4]) {
  unsigned pack = 0;
#pragma unroll
  for (int j = 0; j < 4; ++j) {
    float vn = v[j] + (a[j] - v[j]) * 0.5f;
    bool sp = (vn >= 1.0f);
    v[j] = sp ? 0.0f : vn;
    pack |= (sp ? 1u : 0u) << (8 * j);
  }
  return pack;
}

__global__ void __launch_bounds__(1024, 4)
snn_fb(const float* __restrict__ x,
       const float* __restrict__ W1, const float* __restrict__ R1,
       const float* __restrict__ W2, const float* __restrict__ R2,
       const float* __restrict__ W3, const float* __restrict__ R3,
       unsigned char* __restrict__ sb, unsigned* __restrict__ bar,
       float* __restrict__ out)
{
  extern __shared__ float4 red[];
  const int tid = threadIdx.x;
  const int b   = tid & 255;
  const int ks  = __builtin_amdgcn_readfirstlane(tid >> 8);
  const int h0  = blockIdx.x * 4;
  const int k0  = ks * 256;
  const int k1  = (ks == 3) ? Hn : (k0 + 256);

  const float* W1r = W1 + (size_t)h0 * Lf;
  const float* R1r = R1 + (size_t)h0 * Hn;
  const float* W2r = W2 + (size_t)h0 * Hn;
  const float* R2r = R2 + (size_t)h0 * Hn;
  const float* W3r = W3 + (size_t)h0 * Hn;
  const float* R3r = R3 + (size_t)h0 * Hn;

  float v1[4], v2[4], v3[4];
#pragma unroll
  for (int j = 0; j < 4; ++j) { v1[j] = 0.f; v2[j] = 0.f; v3[j] = 0.f; }
  const float* xb = x + (size_t)b * (Lf * Tt);

  for (int p = 0; p < Tt + 2; ++p) {
    const int srd = (p + 1) & 1;
    const int swr = p & 1;
    float a1[4] = {0,0,0,0}, a2[4] = {0,0,0,0}, a3[4] = {0,0,0,0};
    const bool l1on = (p < Tt), l2on = (p >= 1) && (p <= Tt), l3on = (p >= 2);

    if (l1on) {
      if (ks == 3) {
#pragma unroll
        for (int t = 0; t < Lf; ++t) {
          float xv = xb[(size_t)t * Tt + p];
#pragma unroll
          for (int j = 0; j < 4; ++j) a1[j] = fmaf(W1r[j * Lf + t], xv, a1[j]);
        }
      }
      fb_accum(a1, sb + fb_srow(srd, 0, b), R1r, k0, k1);
    }
    if (l2on) {
      fb_accum(a2, sb + fb_srow(srd, 0, b), W2r, k0, k1);
      fb_accum(a2, sb + fb_srow(srd, 1, b), R2r, k0, k1);
    }
    if (l3on) {
      fb_accum(a3, sb + fb_srow(srd, 1, b), W3r, k0, k1);
      fb_accum(a3, sb + fb_srow(srd, 2, b), R3r, k0, k1);
    }

    if (ks != 0) {
      if (l1on) red[(0 * 3 + ks - 1) * Bsz + b] = make_float4(a1[0], a1[1], a1[2], a1[3]);
      if (l2on) red[(1 * 3 + ks - 1) * Bsz + b] = make_float4(a2[0], a2[1], a2[2], a2[3]);
      if (l3on) red[(2 * 3 + ks - 1) * Bsz + b] = make_float4(a3[0], a3[1], a3[2], a3[3]);
    }
    __syncthreads();

    if (ks == 0) {
      if (l1on) {
#pragma unroll
        for (int q = 0; q < 3; ++q) {
          float4 r = red[(0 * 3 + q) * Bsz + b];
          a1[0] += r.x; a1[1] += r.y; a1[2] += r.z; a1[3] += r.w;
        }
        fb_store4(sb + fb_srow(swr, 0, b) + h0, fb_lif(v1, a1));
      }
      if (l2on) {
#pragma unroll
        for (int q = 0; q < 3; ++q) {
          float4 r = red[(1 * 3 + q) * Bsz + b];
          a2[0] += r.x; a2[1] += r.y; a2[2] += r.z; a2[3] += r.w;
        }
        fb_store4(sb + fb_srow(swr, 1, b) + h0, fb_lif(v2, a2));
      }
      if (l3on) {
#pragma unroll
        for (int q = 0; q < 3; ++q) {
          float4 r = red[(2 * 3 + q) * Bsz + b];
          a3[0] += r.x; a3[1] += r.y; a3[2] += r.z; a3[3] += r.w;
        }
        fb_store4(sb + fb_srow(swr, 2, b) + h0, fb_lif(v3, a3));
      }
    }

    asm volatile("s_waitcnt vmcnt(0)" ::: "memory");
    __syncthreads();
    if (tid == 0) {
      __hip_atomic_fetch_add(bar, 1u, __ATOMIC_RELAXED, __HIP_MEMORY_SCOPE_AGENT);
      const unsigned tgt = (unsigned)(p + 1) * FB_NBLK;
      while (__hip_atomic_load(bar, __ATOMIC_RELAXED, __HIP_MEMORY_SCOPE_AGENT) < tgt) {}
    }
    __syncthreads();
  }

  if (ks == 0) {
    float4 o = make_float4(expf(v3[0]), expf(v3[1]), expf(v3[2]), expf(v3[3]));
    *(float4*)(out + (size_t)b * Hn + h0) = o;
  }
}

// ======================= launcher =======================
extern "C" void kernel_launch(void* const* d_in, const int* in_sizes, int n_in,
                              void* d_out, int out_size, void* d_ws, size_t ws_size,
                              hipStream_t stream) {
  const float* x  = (const float*)d_in[0];
  const float* W1 = (const float*)d_in[1];
  const float* R1 = (const float*)d_in[2];
  const float* W2 = (const float*)d_in[3];
  const float* R2 = (const float*)d_in[4];
  const float* W3 = (const float*)d_in[5];
  const float* R3 = (const float*)d_in[6];
  float* out = (float*)d_out;
  unsigned char* ws = (unsigned char*)d_ws;

  hipFuncSetAttribute((const void*)snn_fb,
                      hipFuncAttributeMaxDynamicSharedMemorySize, (int)FB_SMEM);

  if (ws_size >= WS_NEED) {
    // bf16 weight prep + zero spike slots/barrier
    hipLaunchKernelGGL(prep_w, dim3(20480), dim3(256), 0, stream,
                       R1, W2, R2, W3, R3, ws);
    hipMemsetAsync(ws + SB_OFF, 0, SB_BYTES + 64, stream);
    void* args[] = { (void*)&x, (void*)&W1, (void*)&ws, (void*)&out };
    hipError_t e = hipLaunchCooperativeKernel((const void*)snn_mfma, dim3(NBLK),
                                              dim3(256), args, 0, stream);
    if (e == hipSuccess) return;
  }

  // fallback: proven VALU path (spikes at ws[0])
  unsigned char* sbytes = ws;
  unsigned* bar = (unsigned*)(ws + FB_SB_BYTES);
  hipMemsetAsync(ws, 0, FB_SB_BYTES + 64, stream);
  void* fargs[] = { (void*)&x, (void*)&W1, (void*)&R1, (void*)&W2, (void*)&R2,
                    (void*)&W3, (void*)&R3, (void*)&sbytes, (void*)&bar,
                    (void*)&out };
  hipLaunchCooperativeKernel((const void*)snn_fb, dim3(FB_NBLK), dim3(1024),
                             fargs, FB_SMEM, stream);
}